// Round 6
// baseline (174.242 us; speedup 1.0000x reference)
//
#include <hip/hip_runtime.h>
#include <hip/hip_bf16.h>

// y_i = x_i^T Q x_i + b^T x_i + c ; N=16384, D=1024, fp32.
// Round 6: shrink A-residency to KH=128 (K-split 8) at R=64 rows/wave ->
// A-frags = 64 AGPR (was 128), freeing ~80 VGPRs for real pipelining.
// No column split (x A-prologue halves to 64 MB). Grid = 64 rblk x 8 kq =
// 512 blocks = 2/CU at __launch_bounds__(256,2) (budget 256 regs: 64 AGPR +
// ~140 VGPR). Two 16-n tiles per barrier (32 barriers); per phase, Q-pf for
// the NEXT phase and BOTH tiles' fused-dot x-columns are issued right after
// the barrier -> xv gets 1-2 full MFMA phases of latency cover (round 4/5's
// 17% MfmaUtil came from per-tile serial chains that 2-wave/SIMD occupancy
// cannot hide). LDS share ratio stays 1 ds_read_b128 : 4 MFMA.

#define DD 1024
#define KH 128           // K per block (K-split 8)
#define KSTEP 4          // KH/32 MFMA k-steps per 16-n tile
#define NPH 32           // phases; each phase = 2 tiles = 32 Q rows
#define LDS_ROW 136      // shorts: 128 + 8 pad (272 B; 68 dw = 4 mod 32 banks)

typedef short v8s __attribute__((ext_vector_type(8)));
typedef float v4f __attribute__((ext_vector_type(4)));

__device__ __forceinline__ short f2b(float f) {
    union { __hip_bfloat16 h; short s; } u;
    u.h = __float2bfloat16(f);
    return u.s;
}

__global__ __launch_bounds__(256, 2)
void quad_kernel(const float* __restrict__ x, const float* __restrict__ Q,
                 const float* __restrict__ bvec, const float* __restrict__ cptr,
                 float* __restrict__ y)
{
    __shared__ short lq[2][32 * LDS_ROW];   // 2 x 8.5 KB (32 Q-rows x 128 k)

    const int tid  = threadIdx.x;
    const int lane = tid & 63;
    const int wave = tid >> 6;
    const int quad = lane >> 4;
    const int l15  = lane & 15;

    const int kq   = blockIdx.x & 7;     // K eighth
    const int rblk = blockIdx.x >> 3;    // 0..63

    const int row_base = rblk * 256 + wave * 64;   // 64 rows per wave
    const int kofs = kq * KH;

    // ---- Staging map: phase = 32 Qrows x 128 floats = 1024 float4 / 256 thr
    int s_nn[4], s_k4[4];
    #pragma unroll
    for (int i = 0; i < 4; ++i) {
        const int idx = tid + i * 256;
        s_nn[i] = idx >> 5;        // 0..31
        s_k4[i] = idx & 31;        // float4 within KH
    }

    // prefetch phase 0 (in flight across the A-load prologue)
    float4 pf[4];
    #pragma unroll
    for (int i = 0; i < 4; ++i)
        pf[i] = *(const float4*)(Q + (size_t)s_nn[i] * DD + kofs + s_k4[i] * 4);

    // ---- Prologue: A = x[64 rows][kofs..kofs+128) bf16 frags in AGPRs ----
    // A layout (16x16x32): m = lane&15, k = quad*8 + j (8 contiguous bf16)
    v8s a[4][KSTEP];
    #pragma unroll
    for (int g = 0; g < 4; ++g) {
        const float* xr = x + (size_t)(row_base + g * 16 + l15) * DD + kofs + quad * 8;
        #pragma unroll
        for (int s = 0; s < KSTEP; ++s) {
            const float4 f0 = *(const float4*)(xr + s * 32);
            const float4 f1 = *(const float4*)(xr + s * 32 + 4);
            v8s t;
            t[0]=f2b(f0.x); t[1]=f2b(f0.y); t[2]=f2b(f0.z); t[3]=f2b(f0.w);
            t[4]=f2b(f1.x); t[5]=f2b(f1.y); t[6]=f2b(f1.z); t[7]=f2b(f1.w);
            a[g][s] = t;
            asm volatile("" : "+a"(a[g][s]));   // pin to AGPR
        }
    }

    float acc[4][4];
    #pragma unroll
    for (int g = 0; g < 4; ++g)
        #pragma unroll
        for (int r = 0; r < 4; ++r) acc[g][r] = 0.f;

    for (int p = 0; p < NPH; ++p) {
        // ---- store staged 32-row Q chunk (fp32 -> bf16) into buf p&1 ----
        short* dst = &lq[p & 1][0];
        #pragma unroll
        for (int i = 0; i < 4; ++i) {
            const float4 f = pf[i];
            short4 s;
            s.x=f2b(f.x); s.y=f2b(f.y); s.z=f2b(f.z); s.w=f2b(f.w);
            *(short4*)&dst[s_nn[i] * LDS_ROW + s_k4[i] * 4] = s;
        }
        __syncthreads();

        // ---- issue next phase's Q prefetch (full phase of flight time) ----
        if (p + 1 < NPH) {
            #pragma unroll
            for (int i = 0; i < 4; ++i)
                pf[i] = *(const float4*)(Q + (size_t)((p + 1) * 32 + s_nn[i]) * DD + kofs + s_k4[i] * 4);
        }

        // ---- issue BOTH tiles' fused-dot operands up front ----
        const int n0 = p * 32 + l15;        // tile 0 column
        const int n1 = n0 + 16;             // tile 1 column
        const float bn0 = (kq == 0) ? bvec[n0] : 0.f;
        const float bn1 = (kq == 0) ? bvec[n1] : 0.f;
        float xv0[4][4], xv1[4][4];
        {
            const float* xc = x + (size_t)(row_base + quad * 4) * DD;
            #pragma unroll
            for (int g = 0; g < 4; ++g)
                #pragma unroll
                for (int r = 0; r < 4; ++r) {
                    const size_t ro = (size_t)(g * 16 + r) * DD;
                    xv0[g][r] = xc[ro + n0];
                    xv1[g][r] = xc[ro + n1];
                }
        }

        // ---- tile 0: rows 0..15 of the staged chunk ----
        {
            v4f cf[4];
            #pragma unroll
            for (int g = 0; g < 4; ++g) cf[g] = (v4f){0.f, 0.f, 0.f, 0.f};
            const short* bp = &lq[p & 1][l15 * LDS_ROW + quad * 8];
            #pragma unroll
            for (int s = 0; s < KSTEP; ++s) {
                const v8s bfrag = *(const v8s*)(bp + s * 32);
                #pragma unroll
                for (int g = 0; g < 4; ++g)
                    cf[g] = __builtin_amdgcn_mfma_f32_16x16x32_bf16(a[g][s], bfrag, cf[g], 0, 0, 0);
            }
            #pragma unroll
            for (int g = 0; g < 4; ++g)
                #pragma unroll
                for (int r = 0; r < 4; ++r)
                    acc[g][r] += (cf[g][r] + bn0) * xv0[g][r];
        }

        // ---- tile 1: rows 16..31 of the staged chunk ----
        {
            v4f cf[4];
            #pragma unroll
            for (int g = 0; g < 4; ++g) cf[g] = (v4f){0.f, 0.f, 0.f, 0.f};
            const short* bp = &lq[p & 1][(16 + l15) * LDS_ROW + quad * 8];
            #pragma unroll
            for (int s = 0; s < KSTEP; ++s) {
                const v8s bfrag = *(const v8s*)(bp + s * 32);
                #pragma unroll
                for (int g = 0; g < 4; ++g)
                    cf[g] = __builtin_amdgcn_mfma_f32_16x16x32_bf16(a[g][s], bfrag, cf[g], 0, 0, 0);
            }
            #pragma unroll
            for (int g = 0; g < 4; ++g)
                #pragma unroll
                for (int r = 0; r < 4; ++r)
                    acc[g][r] += (cf[g][r] + bn1) * xv1[g][r];
        }
    }

    // ---- reduce across the 16 lanes of each quad, atomic into y ----
    const float cc = (kq == 0) ? cptr[0] : 0.f;  // c once per row (kq0 block)
    #pragma unroll
    for (int g = 0; g < 4; ++g) {
        #pragma unroll
        for (int r = 0; r < 4; ++r) {
            float v = acc[g][r];
            v += __shfl_xor(v, 1); v += __shfl_xor(v, 2);
            v += __shfl_xor(v, 4); v += __shfl_xor(v, 8);
            if (l15 == 0)
                atomicAdd(&y[row_base + g * 16 + quad * 4 + r], v + cc);
        }
    }
}

extern "C" void kernel_launch(void* const* d_in, const int* in_sizes, int n_in,
                              void* d_out, int out_size, void* d_ws, size_t ws_size,
                              hipStream_t stream)
{
    const float* x = (const float*)d_in[0];
    const float* Q = (const float*)d_in[1];
    const float* b = (const float*)d_in[2];
    const float* c = (const float*)d_in[3];
    float* y = (float*)d_out;

    hipMemsetAsync(y, 0, (size_t)out_size * sizeof(float), stream);
    quad_kernel<<<dim3(512), dim3(256), 0, stream>>>(x, Q, b, c, y);
}

// Round 7
// 166.837 us; speedup vs baseline: 1.0444x; 1.0444x over previous
//
#include <hip/hip_runtime.h>
#include <hip/hip_bf16.h>

// y_i = x_i^T Q x_i + b^T x_i + c ; N=16384, D=1024, fp32.
// Round 7: break the 8-waves/CU plateau (r2/r4/r5/r6 all 77-92us, MfmaUtil
// 14-18%). KH=128 @ R=64 rows/wave -> A-frags = 64 AGPR; col-split 2 keeps
// the xv stream at 256 MB (r6's 512 MB regressed). Grid = 64 rblk x 8 kq x
// 2 cs = 1024 blocks, __launch_bounds__(256,3) -> 12 waves/CU (16 if alloc
// lands <=128). Pre-pass converts Q->bf16 into d_ws; staging via
// global_load_lds 16B DMA (no staging VGPRs/VALU) into an XOR-swizzled
// unpadded LDS layout (chunk ^= row&7): DMA requires contiguous lane order
// (no pad possible), swizzle restores conflict-free ds_read_b128.

#define DD 1024
#define KH 128            // K per block (K-split 8)
#define NPH 16            // phases per block: n-range 512 / 32 rows-per-phase
#define BUF_SHORTS 4096   // 32 Q-rows x 128 k, unpadded

typedef short v8s __attribute__((ext_vector_type(8)));
typedef float v4f __attribute__((ext_vector_type(4)));

#define AS1(p) ((const __attribute__((address_space(1))) void*)(p))
#define AS3(p) ((__attribute__((address_space(3))) void*)(p))

__device__ __forceinline__ short f2b(float f) {
    union { __hip_bfloat16 h; short s; } u;
    u.h = __float2bfloat16(f);
    return u.s;
}

// ---- pre-pass: Q fp32 -> bf16 (row-major) into workspace ----
__global__ __launch_bounds__(256)
void convert_q(const float* __restrict__ Q, short* __restrict__ qb)
{
    const int i = blockIdx.x * 256 + threadIdx.x;   // 262144 float4s exactly
    const float4 f = ((const float4*)Q)[i];
    short4 s;
    s.x = f2b(f.x); s.y = f2b(f.y); s.z = f2b(f.z); s.w = f2b(f.w);
    ((short4*)qb)[i] = s;
}

template<bool PRE>
__device__ __forceinline__
void quad_body(const float* __restrict__ x, const float* __restrict__ Qf,
               const short* __restrict__ Qb, const float* __restrict__ bvec,
               const float* __restrict__ cptr, float* __restrict__ y)
{
    __shared__ short lq[2][BUF_SHORTS];   // 2 x 8 KB

    const int tid  = threadIdx.x;
    const int lane = tid & 63;
    const int quad = lane >> 4;
    const int l15  = lane & 15;
    const int wave = tid >> 6;

    const int seg  = blockIdx.x & 15;    // kq*2 + cs
    const int rblk = blockIdx.x >> 4;    // 0..63
    const int kq   = seg >> 1;           // K eighth
    const int cs   = seg & 1;            // column half

    const int row_base = rblk * 256 + wave * 64;   // 64 rows per wave
    const int kofs   = kq * KH;
    const int nbase0 = cs * 512;

    // ---- staging slot map: 512 16B-slots per phase, 2 per thread ----
    // slot -> (row = slot>>4, cpos = slot&15); LDS[row][cpos] holds global
    // chunk (cpos ^ (row&7)) of that Q row (XOR swizzle, bank-conflict-free).
    int srow[2], schunk[2];
    #pragma unroll
    for (int i = 0; i < 2; ++i) {
        const int slot = i * 256 + tid;
        const int r = slot >> 4, cp = slot & 15;
        srow[i] = r;
        schunk[i] = cp ^ (r & 7);
    }

    float4 pf[4];   // fallback-path staging regs (unused when PRE)

    // ---- issue phase-0 staging (in flight across the A prologue) ----
    if (PRE) {
        #pragma unroll
        for (int i = 0; i < 2; ++i) {
            const short* src = Qb + (size_t)(nbase0 + srow[i]) * DD + kofs + schunk[i] * 8;
            __builtin_amdgcn_global_load_lds(AS1(src), AS3(&lq[0][(i * 256 + tid) * 8]), 16, 0, 0);
        }
    } else {
        #pragma unroll
        for (int i = 0; i < 2; ++i) {
            const float* src = Qf + (size_t)(nbase0 + srow[i]) * DD + kofs + schunk[i] * 8;
            pf[i * 2 + 0] = *(const float4*)(src);
            pf[i * 2 + 1] = *(const float4*)(src + 4);
        }
    }

    // ---- A prologue: x[64 rows][kofs..kofs+128) bf16 frags in AGPRs ----
    // A layout (16x16x32): m = lane&15, k = quad*8 + j (8 contiguous bf16)
    v8s a[4][4];
    #pragma unroll
    for (int g = 0; g < 4; ++g) {
        const float* xr = x + (size_t)(row_base + g * 16 + l15) * DD + kofs + quad * 8;
        #pragma unroll
        for (int s = 0; s < 4; ++s) {
            const float4 f0 = *(const float4*)(xr + s * 32);
            const float4 f1 = *(const float4*)(xr + s * 32 + 4);
            v8s t;
            t[0]=f2b(f0.x); t[1]=f2b(f0.y); t[2]=f2b(f0.z); t[3]=f2b(f0.w);
            t[4]=f2b(f1.x); t[5]=f2b(f1.y); t[6]=f2b(f1.z); t[7]=f2b(f1.w);
            a[g][s] = t;
            asm volatile("" : "+a"(a[g][s]));   // pin to AGPR
        }
    }

    float acc[4][4];
    #pragma unroll
    for (int g = 0; g < 4; ++g)
        #pragma unroll
        for (int r = 0; r < 4; ++r) acc[g][r] = 0.f;

    for (int p = 0; p < NPH; ++p) {
        if (!PRE) {
            // commit staged fp32->bf16 into buf p&1 before the barrier
            #pragma unroll
            for (int i = 0; i < 2; ++i) {
                const float4 f0 = pf[i * 2 + 0];
                const float4 f1 = pf[i * 2 + 1];
                v8s t;
                t[0]=f2b(f0.x); t[1]=f2b(f0.y); t[2]=f2b(f0.z); t[3]=f2b(f0.w);
                t[4]=f2b(f1.x); t[5]=f2b(f1.y); t[6]=f2b(f1.z); t[7]=f2b(f1.w);
                *(v8s*)&lq[p & 1][(i * 256 + tid) * 8] = t;
            }
        }
        __syncthreads();   // buf p&1 ready (drains DMA / commits writes)

        // issue next phase's staging into the other buffer
        if (p + 1 < NPH) {
            const size_t base = (size_t)(nbase0 + (p + 1) * 32) * DD + kofs;
            if (PRE) {
                #pragma unroll
                for (int i = 0; i < 2; ++i) {
                    const short* src = Qb + base + (size_t)srow[i] * DD + schunk[i] * 8;
                    __builtin_amdgcn_global_load_lds(AS1(src),
                        AS3(&lq[(p + 1) & 1][(i * 256 + tid) * 8]), 16, 0, 0);
                }
            } else {
                #pragma unroll
                for (int i = 0; i < 2; ++i) {
                    const float* src = Qf + base + (size_t)srow[i] * DD + schunk[i] * 8;
                    pf[i * 2 + 0] = *(const float4*)(src);
                    pf[i * 2 + 1] = *(const float4*)(src + 4);
                }
            }
        }

        // ---- two 16-n tiles from the staged 32 rows ----
        #pragma unroll
        for (int tau = 0; tau < 2; ++tau) {
            const int n = nbase0 + p * 32 + tau * 16 + l15;
            const float bn = (kq == 0) ? bvec[n] : 0.f;

            // fused-dot operands (fp32 x columns; covered by MFMA latency)
            float xv[4][4];
            {
                const float* xc = x + (size_t)(row_base + quad * 4) * DD + n;
                #pragma unroll
                for (int g = 0; g < 4; ++g)
                    #pragma unroll
                    for (int r = 0; r < 4; ++r)
                        xv[g][r] = xc[(size_t)(g * 16 + r) * DD];
            }

            v4f cf[4];
            #pragma unroll
            for (int g = 0; g < 4; ++g) cf[g] = (v4f){0.f, 0.f, 0.f, 0.f};

            #pragma unroll
            for (int s = 0; s < 4; ++s) {
                // logical chunk = quad + 4s ; stored at chunk ^ (row&7)
                const int phys = (quad + 4 * s) ^ (l15 & 7);
                const v8s bf = *(const v8s*)&lq[p & 1][((tau * 16 + l15) << 7) + (phys << 3)];
                #pragma unroll
                for (int g = 0; g < 4; ++g)
                    cf[g] = __builtin_amdgcn_mfma_f32_16x16x32_bf16(a[g][s], bf, cf[g], 0, 0, 0);
            }

            // fused dot: C layout col = lane&15, row = quad*4 + reg
            #pragma unroll
            for (int g = 0; g < 4; ++g)
                #pragma unroll
                for (int r = 0; r < 4; ++r)
                    acc[g][r] += (cf[g][r] + bn) * xv[g][r];
        }
    }

    // ---- reduce across the 16 lanes of each quad, atomic into y ----
    const float cc = (seg == 0) ? cptr[0] : 0.f;  // c added once per row
    #pragma unroll
    for (int g = 0; g < 4; ++g) {
        #pragma unroll
        for (int r = 0; r < 4; ++r) {
            float v = acc[g][r];
            v += __shfl_xor(v, 1); v += __shfl_xor(v, 2);
            v += __shfl_xor(v, 4); v += __shfl_xor(v, 8);
            if (l15 == 0)
                atomicAdd(&y[row_base + g * 16 + quad * 4 + r], v + cc);
        }
    }
}

__global__ __launch_bounds__(256, 3)
void quad_pre(const float* __restrict__ x, const short* __restrict__ Qb,
              const float* __restrict__ bvec, const float* __restrict__ cptr,
              float* __restrict__ y)
{
    quad_body<true>(x, nullptr, Qb, bvec, cptr, y);
}

__global__ __launch_bounds__(256, 2)
void quad_fp32(const float* __restrict__ x, const float* __restrict__ Qf,
               const float* __restrict__ bvec, const float* __restrict__ cptr,
               float* __restrict__ y)
{
    quad_body<false>(x, Qf, nullptr, bvec, cptr, y);
}

extern "C" void kernel_launch(void* const* d_in, const int* in_sizes, int n_in,
                              void* d_out, int out_size, void* d_ws, size_t ws_size,
                              hipStream_t stream)
{
    const float* x = (const float*)d_in[0];
    const float* Q = (const float*)d_in[1];
    const float* b = (const float*)d_in[2];
    const float* c = (const float*)d_in[3];
    float* y = (float*)d_out;

    hipMemsetAsync(y, 0, (size_t)out_size * sizeof(float), stream);

    if (ws_size >= (size_t)DD * DD * sizeof(short)) {
        short* qb = (short*)d_ws;
        convert_q<<<dim3(1024), dim3(256), 0, stream>>>(Q, qb);
        quad_pre<<<dim3(1024), dim3(256), 0, stream>>>(x, qb, b, c, y);
    } else {
        quad_fp32<<<dim3(1024), dim3(256), 0, stream>>>(x, Q, b, c, y);
    }
}